// Round 1
// baseline (793.756 us; speedup 1.0000x reference)
//
#include <hip/hip_runtime.h>

typedef unsigned short u16;
typedef __bf16 bf16x8 __attribute__((ext_vector_type(8)));
typedef float f32x4 __attribute__((ext_vector_type(4)));

#define MFMA(a, b, c) __builtin_amdgcn_mfma_f32_16x16x32_bf16(a, b, c, 0, 0, 0)

static __device__ __forceinline__ u16 f2bf(float f) {
  unsigned u = __float_as_uint(f);
  u = u + 0x7FFFu + ((u >> 16) & 1u);   // round-to-nearest-even
  return (u16)(u >> 16);
}

static __device__ __forceinline__ f32x4 fzero() {
  f32x4 z; z[0] = 0.f; z[1] = 0.f; z[2] = 0.f; z[3] = 0.f; return z;
}

// ---- kernel 0: convert qkv_w (196608) + proj_w (65536) fp32 -> bf16 into ws ----
__global__ void cvt_w(const float* __restrict__ qw, const float* __restrict__ pw,
                      u16* __restrict__ o) {
  int i = blockIdx.x * 256 + threadIdx.x;      // grid covers 262144 exactly
  float v = (i < 196608) ? qw[i] : pw[i - 196608];
  o[i] = f2bf(v);
}

// LDS layout (u16 units), dynamic 152576 B:
//   Xs  [64][264]           @ 0          (16896)  -- aliased as Os after barrier 2
//   per head h (h = wave):  @ 16896 + h*7424
//     Qs [64][40]  (2560) ; Ks [64][40] (2560) ; Vt [32][72] (2304)
//     P  [64][72]  (4608)  overlays Qs+Ks after S is consumed (in-wave only)
#define SMEM_U16 76288

// one window per block; 8 waves; wave h owns head h end-to-end (no cross-wave
// attention deps -> 3 barriers total instead of 14)
__global__ __launch_bounds__(512, 2) void swin(
    const float* __restrict__ x, const u16* __restrict__ wqkv,
    const u16* __restrict__ wproj, const float* __restrict__ pb,
    const float* __restrict__ bias, float* __restrict__ out) {

  extern __shared__ u16 smem[];

  const int tid  = threadIdx.x;
  const int wv   = tid >> 6;            // wave id == head id
  const int lane = tid & 63;
  const int l15  = lane & 15;
  const int quad = lane >> 4;

  const int w  = blockIdx.x;            // 4096 windows
  const int bb = w >> 10;
  const int wh = (w >> 5) & 31;
  const int ww = w & 31;

  u16* Xs = smem;

  // ---- stage x window -> bf16 LDS (coalesced float4) ----
  {
    const float* xb = x + ((size_t)bb << 24);
    #pragma unroll
    for (int i = 0; i < 8; ++i) {
      int flat = i * 512 + tid;          // 0..4095 float4s
      int t  = flat >> 6;                // token 0..63
      int c4 = flat & 63;                // float4 within token
      int row = wh * 8 + (t >> 3), col = ww * 8 + (t & 7);
      const float4 v = *(const float4*)(xb + ((size_t)(row * 256 + col) << 8) + c4 * 4);
      unsigned p0 = (unsigned)f2bf(v.x) | ((unsigned)f2bf(v.y) << 16);
      unsigned p1 = (unsigned)f2bf(v.z) | ((unsigned)f2bf(v.w) << 16);
      *(uint2*)&Xs[t * 264 + c4 * 4] = make_uint2(p0, p1);
    }
  }
  __syncthreads();                       // barrier 1: Xs ready

  u16* Qs = smem + 16896 + wv * 7424;
  u16* Ks = Qs + 2560;
  u16* Vt = Qs + 5120;

  // ---- QKV GEMM for head wv: 6 N-tiles {q0,q1,k0,k1,v0,v1}, M=64, K=256 ----
  {
    f32x4 acc[6][4];
    #pragma unroll
    for (int j = 0; j < 6; ++j)
      #pragma unroll
      for (int m = 0; m < 4; ++m) acc[j][m] = fzero();

    #pragma unroll
    for (int kk = 0; kk < 8; ++kk) {
      bf16x8 af[4];
      #pragma unroll
      for (int m = 0; m < 4; ++m)
        af[m] = *(const bf16x8*)&Xs[(m * 16 + l15) * 264 + kk * 32 + quad * 8];
      #pragma unroll
      for (int j = 0; j < 6; ++j) {
        int ty = j >> 1, sub = j & 1;
        int r0 = ty * 256 + wv * 32 + sub * 16;    // qkv_w row base
        bf16x8 bf = *(const bf16x8*)(wqkv + (size_t)(r0 + l15) * 256 + kk * 32 + quad * 8);
        #pragma unroll
        for (int m = 0; m < 4; ++m) acc[j][m] = MFMA(af[m], bf, acc[j][m]);
      }
    }
    // epilogue: Q,K tok-major [64][40]; V transposed [32][72]
    #pragma unroll
    for (int j = 0; j < 6; ++j) {
      int ty = j >> 1, sub = j & 1;
      int dl = sub * 16 + l15;
      #pragma unroll
      for (int m = 0; m < 4; ++m) {
        if (ty == 2) {
          unsigned p0 = (unsigned)f2bf(acc[j][m][0]) | ((unsigned)f2bf(acc[j][m][1]) << 16);
          unsigned p1 = (unsigned)f2bf(acc[j][m][2]) | ((unsigned)f2bf(acc[j][m][3]) << 16);
          *(uint2*)&Vt[dl * 72 + m * 16 + quad * 4] = make_uint2(p0, p1);
        } else {
          u16* dst = ty ? Ks : Qs;
          #pragma unroll
          for (int e = 0; e < 4; ++e)
            dst[(m * 16 + quad * 4 + e) * 40 + dl] = f2bf(acc[j][m][e]);
        }
      }
    }
  }
  __syncthreads();                       // barrier 2: all Xs reads done (Os overlay safe)

  // ---- S = (Q K^T)*scale + bias ; softmax ; P (bf16) overlays Q/K — all in-wave ----
  const float scale = 0.17677669529663687f;   // 1/sqrt(32)
  float sb[4][4][4];                          // [m][n][e] unnormalized p after softmax
  float rinv[4][4];
  {
    // prefetch bias early so L2 latency hides under the MFMAs
    const float* bh = bias + wv * 4096;
    float bv[4][4][4];
    #pragma unroll
    for (int m = 0; m < 4; ++m)
      #pragma unroll
      for (int n = 0; n < 4; ++n)
        #pragma unroll
        for (int e = 0; e < 4; ++e)
          bv[m][n][e] = bh[(m * 16 + quad * 4 + e) * 64 + n * 16 + l15];

    f32x4 sacc[4][4];
    #pragma unroll
    for (int m = 0; m < 4; ++m)
      #pragma unroll
      for (int n = 0; n < 4; ++n) sacc[m][n] = fzero();

    bf16x8 qa[4];
    #pragma unroll
    for (int m = 0; m < 4; ++m)
      qa[m] = *(const bf16x8*)&Qs[(m * 16 + l15) * 40 + quad * 8];
    #pragma unroll
    for (int n = 0; n < 4; ++n) {
      bf16x8 kb = *(const bf16x8*)&Ks[(n * 16 + l15) * 40 + quad * 8];
      #pragma unroll
      for (int m = 0; m < 4; ++m) sacc[m][n] = MFMA(qa[m], kb, sacc[m][n]);
    }
    #pragma unroll
    for (int m = 0; m < 4; ++m)
      #pragma unroll
      for (int n = 0; n < 4; ++n)
        #pragma unroll
        for (int e = 0; e < 4; ++e)
          sb[m][n][e] = sacc[m][n][e] * scale + bv[m][n][e];
  }
  // softmax: row tq = m*16+quad*4+e lives in 16 lanes (l15) x 4 n-values
  #pragma unroll
  for (int m = 0; m < 4; ++m)
    #pragma unroll
    for (int e = 0; e < 4; ++e) {
      float mx = fmaxf(fmaxf(sb[m][0][e], sb[m][1][e]), fmaxf(sb[m][2][e], sb[m][3][e]));
      #pragma unroll
      for (int d = 1; d < 16; d <<= 1) mx = fmaxf(mx, __shfl_xor(mx, d, 64));
      float sum = 0.f;
      #pragma unroll
      for (int n = 0; n < 4; ++n) {
        float p = __expf(sb[m][n][e] - mx);
        sb[m][n][e] = p; sum += p;
      }
      #pragma unroll
      for (int d = 1; d < 16; d <<= 1) sum += __shfl_xor(sum, d, 64);
      rinv[m][e] = __builtin_amdgcn_rcpf(sum);
    }
  // write P (in-wave overlay of Q/K; DS ops in-order within wave)
  u16* Ps = Qs;
  #pragma unroll
  for (int m = 0; m < 4; ++m)
    #pragma unroll
    for (int n = 0; n < 4; ++n)
      #pragma unroll
      for (int e = 0; e < 4; ++e)
        Ps[(m * 16 + quad * 4 + e) * 72 + n * 16 + l15] = f2bf(sb[m][n][e]);

  // ---- O = P V (normalize by rinv), write into Os (= Xs alias) ----
  {
    f32x4 oacc[4][2];
    #pragma unroll
    for (int m = 0; m < 4; ++m)
      #pragma unroll
      for (int n = 0; n < 2; ++n) oacc[m][n] = fzero();
    #pragma unroll
    for (int kk = 0; kk < 2; ++kk) {
      bf16x8 pa[4];
      #pragma unroll
      for (int m = 0; m < 4; ++m)
        pa[m] = *(const bf16x8*)&Ps[(m * 16 + l15) * 72 + kk * 32 + quad * 8];
      #pragma unroll
      for (int n = 0; n < 2; ++n) {
        bf16x8 vb = *(const bf16x8*)&Vt[(n * 16 + l15) * 72 + kk * 32 + quad * 8];
        #pragma unroll
        for (int m = 0; m < 4; ++m) oacc[m][n] = MFMA(pa[m], vb, oacc[m][n]);
      }
    }
    u16* Os = Xs;
    #pragma unroll
    for (int m = 0; m < 4; ++m)
      #pragma unroll
      for (int n = 0; n < 2; ++n)
        #pragma unroll
        for (int e = 0; e < 4; ++e)
          Os[(m * 16 + quad * 4 + e) * 264 + wv * 32 + n * 16 + l15] =
              f2bf(oacc[m][n][e] * rinv[m][e]);
  }
  __syncthreads();                       // barrier 3: Os complete

  // ---- proj GEMM + bias, fp32 scatter store; wave wv owns 32 out channels ----
  {
    u16* Os = Xs;
    f32x4 pacc[4][2];
    #pragma unroll
    for (int m = 0; m < 4; ++m)
      #pragma unroll
      for (int n = 0; n < 2; ++n) pacc[m][n] = fzero();
    const int n0 = wv * 32;
    #pragma unroll
    for (int kk = 0; kk < 8; ++kk) {
      bf16x8 af[4];
      #pragma unroll
      for (int m = 0; m < 4; ++m)
        af[m] = *(const bf16x8*)&Os[(m * 16 + l15) * 264 + kk * 32 + quad * 8];
      #pragma unroll
      for (int n = 0; n < 2; ++n) {
        bf16x8 bf = *(const bf16x8*)(wproj + (size_t)(n0 + n * 16 + l15) * 256 + kk * 32 + quad * 8);
        #pragma unroll
        for (int m = 0; m < 4; ++m) pacc[m][n] = MFMA(af[m], bf, pacc[m][n]);
      }
    }
    float* ob = out + ((size_t)bb << 24);
    #pragma unroll
    for (int n = 0; n < 2; ++n) {
      float bvv = pb[n0 + n * 16 + l15];
      #pragma unroll
      for (int m = 0; m < 4; ++m)
        #pragma unroll
        for (int e = 0; e < 4; ++e) {
          int t = m * 16 + quad * 4 + e;
          int row = wh * 8 + (t >> 3), col = ww * 8 + (t & 7);
          ob[((size_t)(row * 256 + col) << 8) + n0 + n * 16 + l15] = pacc[m][n][e] + bvv;
        }
    }
  }
}

extern "C" void kernel_launch(void* const* d_in, const int* in_sizes, int n_in,
                              void* d_out, int out_size, void* d_ws, size_t ws_size,
                              hipStream_t stream) {
  const float* x  = (const float*)d_in[0];
  const float* qw = (const float*)d_in[1];
  const float* pw = (const float*)d_in[2];
  const float* pb = (const float*)d_in[3];
  const float* bs = (const float*)d_in[4];
  u16* wbf = (u16*)d_ws;                 // 262144 bf16 = 512 KB of ws

  static bool lds_opt_in = false;
  if (!lds_opt_in) {                     // host-side, capture-safe, once per process
    hipFuncSetAttribute((const void*)swin,
                        hipFuncAttributeMaxDynamicSharedMemorySize, SMEM_U16 * 2);
    lds_opt_in = true;
  }

  cvt_w<<<1024, 256, 0, stream>>>(qw, pw, wbf);
  swin<<<4096, 512, SMEM_U16 * 2, stream>>>(x, wbf, wbf + 196608, pb, bs, (float*)d_out);
}